// Round 1
// baseline (416.671 us; speedup 1.0000x reference)
//
#include <hip/hip_runtime.h>
#include <hip/hip_bf16.h>
#include <math.h>

#define T_SEQ 4096
#define C_EMB 768
#define NHEAD 12
#define HDIM  64

typedef __bf16 bf16;
typedef __bf16 bf16x8 __attribute__((ext_vector_type(8)));
typedef float  f32x4  __attribute__((ext_vector_type(4)));

// ---------------------------------------------------------------- utilities

__device__ __forceinline__ void stage16(const void* g, void* ldsbase) {
  // global -> LDS direct, 16B per lane; LDS dest = wave-uniform base + lane*16
  __builtin_amdgcn_global_load_lds(
      (__attribute__((address_space(1))) const unsigned int*)g,
      (__attribute__((address_space(3))) unsigned int*)ldsbase, 16, 0, 0);
}

// -------------------------------------------------- weight convert+transpose
// W [K][N] f32  ->  Wt [N][K] bf16
__global__ void wt_transpose(const float* __restrict__ W, bf16* __restrict__ Wt,
                             int K, int N) {
  __shared__ float tile[32][33];
  const int n0 = blockIdx.x * 32, k0 = blockIdx.y * 32;
  const int tx = threadIdx.x & 31, ty = threadIdx.x >> 5;  // 256 thr: ty 0..7
#pragma unroll
  for (int i = 0; i < 32; i += 8)
    tile[ty + i][tx] = W[(size_t)(k0 + ty + i) * N + n0 + tx];
  __syncthreads();
#pragma unroll
  for (int i = 0; i < 32; i += 8)
    Wt[(size_t)(n0 + ty + i) * K + k0 + tx] = (bf16)tile[tx][ty + i];
}

// ------------------------------------------------------------------ layernorm
// x [4096][768] f32 -> y bf16
__global__ void ln_rows(const float* __restrict__ x, bf16* __restrict__ y) {
  const int row = blockIdx.x;
  const float* xr = x + (size_t)row * C_EMB;
  const int t = threadIdx.x;  // 256
  float v0 = xr[t], v1 = xr[t + 256], v2 = xr[t + 512];
  float s  = v0 + v1 + v2;
  float ss = v0 * v0 + v1 * v1 + v2 * v2;
#pragma unroll
  for (int m = 1; m < 64; m <<= 1) {
    s += __shfl_xor(s, m);
    ss += __shfl_xor(ss, m);
  }
  __shared__ float bs[4], bq[4];
  const int w = t >> 6;
  if ((t & 63) == 0) { bs[w] = s; bq[w] = ss; }
  __syncthreads();
  s  = bs[0] + bs[1] + bs[2] + bs[3];
  ss = bq[0] + bq[1] + bq[2] + bq[3];
  const float mu  = s * (1.0f / C_EMB);
  const float var = ss * (1.0f / C_EMB) - mu * mu;
  const float rs  = rsqrtf(var + 1e-5f);
  bf16* yr = y + (size_t)row * C_EMB;
  yr[t]       = (bf16)((v0 - mu) * rs);
  yr[t + 256] = (bf16)((v1 - mu) * rs);
  yr[t + 512] = (bf16)((v2 - mu) * rs);
}

// ------------------------------------------------------------------ GEMM
// C[M][N] = A[M][K](bf16 rowmajor) x BT[N][K](bf16)   (i.e. A @ B)
// EPI 0: store bf16        EPI 1: f32 = res + acc
// EPI 2: bf16 = gelu(acc + bias[c])   EPI 3: f32 = res + acc
template <int EPI>
__global__ void gemm_bt(const bf16* __restrict__ A, const bf16* __restrict__ BT,
                        void* __restrict__ Cout, const float* __restrict__ res,
                        const float* __restrict__ bias, int M, int N, int K) {
  __shared__ __align__(16) bf16 As[128 * 32];
  __shared__ __align__(16) bf16 Bs[128 * 32];
  const int row0 = blockIdx.x * 128, col0 = blockIdx.y * 128;
  const int tid = threadIdx.x;
  const int w = tid >> 6, lane = tid & 63;
  const int wr = w >> 1, wc = w & 1;
  const int l15 = lane & 15, l4 = lane >> 4;

  f32x4 acc[4][4];
#pragma unroll
  for (int m = 0; m < 4; m++)
#pragma unroll
    for (int n = 0; n < 4; n++) acc[m][n] = (f32x4){0.f, 0.f, 0.f, 0.f};

  const int rr = lane >> 2;        // 16 rows per 1KB wave-instr
  const int c8 = (lane & 3) * 8;   // 4 chunks of 8 bf16 per 64B row

  for (int k0 = 0; k0 < K; k0 += 32) {
    const bf16* gA = A + (size_t)(row0 + w * 32 + rr) * K + k0 + c8;
    const bf16* gB = BT + (size_t)(col0 + w * 32 + rr) * K + k0 + c8;
    stage16(gA, As + (w * 32) * 32);
    stage16(gA + (size_t)16 * K, As + (w * 32 + 16) * 32);
    stage16(gB, Bs + (w * 32) * 32);
    stage16(gB + (size_t)16 * K, Bs + (w * 32 + 16) * 32);
    __syncthreads();

    bf16x8 af[4], bfv[4];
#pragma unroll
    for (int m = 0; m < 4; m++)
      af[m] = *reinterpret_cast<const bf16x8*>(As + (wr * 64 + m * 16 + l15) * 32 + l4 * 8);
#pragma unroll
    for (int n = 0; n < 4; n++)
      bfv[n] = *reinterpret_cast<const bf16x8*>(Bs + (wc * 64 + n * 16 + l15) * 32 + l4 * 8);
#pragma unroll
    for (int m = 0; m < 4; m++)
#pragma unroll
      for (int n = 0; n < 4; n++)
        acc[m][n] = __builtin_amdgcn_mfma_f32_16x16x32_bf16(af[m], bfv[n], acc[m][n], 0, 0, 0);
    __syncthreads();
  }

  const int orow = row0 + wr * 64;
  const int ocol = col0 + wc * 64;
#pragma unroll
  for (int m = 0; m < 4; m++) {
#pragma unroll
    for (int n = 0; n < 4; n++) {
      const int c = ocol + n * 16 + l15;
#pragma unroll
      for (int j = 0; j < 4; j++) {
        const int r = orow + m * 16 + l4 * 4 + j;  // C/D: col=lane&15, row=(lane>>4)*4+reg
        const size_t idx = (size_t)r * N + c;
        const float v = acc[m][n][j];
        if (EPI == 0) {
          ((bf16*)Cout)[idx] = (bf16)v;
        } else if (EPI == 1) {
          ((float*)Cout)[idx] = res[idx] + v;
        } else if (EPI == 2) {
          const float h = v + bias[c];
          ((bf16*)Cout)[idx] = (bf16)(0.5f * h * (1.0f + erff(h * 0.70710678118f)));
        } else {
          ((float*)Cout)[idx] = res[idx] + v;
        }
      }
    }
  }
}

// ------------------------------------------------------------------ attention
// kqv [T][2304] bf16 : k at +0, q at +768, v at +1536, head offset h*64
// out [T][768] bf16
__global__ void attn_fused(const bf16* __restrict__ kqv, bf16* __restrict__ out) {
  const int qb = blockIdx.x, h = blockIdx.y;
  const int tid = threadIdx.x, w = tid >> 6, lane = tid & 63;
  const int l15 = lane & 15, l4 = lane >> 4;

  __shared__ __align__(16) bf16 Kt[32 * 64];      // [key][d]
  __shared__ __align__(16) bf16 Vt[64 * 32];      // [d][key] chunk-swizzled
  __shared__ __align__(16) bf16 Pb[4][16 * 32];   // per-wave P

  // Q fragments, held in registers for the whole kernel
  const int qrow = qb * 64 + w * 16 + l15;
  const bf16* qp = kqv + (size_t)qrow * 2304 + 768 + h * 64 + l4 * 8;
  const bf16x8 qf0 = *reinterpret_cast<const bf16x8*>(qp);
  const bf16x8 qf1 = *reinterpret_cast<const bf16x8*>(qp + 32);

  float mrow[4], lrow[4];
  f32x4 accO[4];
#pragma unroll
  for (int r = 0; r < 4; r++) { mrow[r] = -1e30f; lrow[r] = 0.f; }
#pragma unroll
  for (int dc = 0; dc < 4; dc++) accO[dc] = (f32x4){0.f, 0.f, 0.f, 0.f};

  const int sr = tid >> 3, sc8 = (tid & 7) * 8;  // staging: 32 rows x 8 chunks

  for (int kt = 0; kt < T_SEQ / 32; kt++) {
    __syncthreads();
    {
      const bf16* kp = kqv + (size_t)(kt * 32 + sr) * 2304 + h * 64 + sc8;
      *reinterpret_cast<bf16x8*>(Kt + sr * 64 + sc8) =
          *reinterpret_cast<const bf16x8*>(kp);
      const bf16x8 vv = *reinterpret_cast<const bf16x8*>(kp + 1536);  // V row
#pragma unroll
      for (int e = 0; e < 8; e++) {
        const int d = sc8 + e;
        // transposed, 16B-chunk XOR swizzle on key-chunk index
        Vt[d * 32 + (((sr >> 3) ^ ((d >> 3) & 3)) * 8) + (sr & 7)] = vv[e];
      }
    }
    __syncthreads();

    // S = (Q Kt^T) * scale : two 16-key fragments, K(reduction)=64 via 2 MFMA
    f32x4 s0 = (f32x4){0.f, 0.f, 0.f, 0.f}, s1 = s0;
    {
      const bf16x8 kf00 = *reinterpret_cast<const bf16x8*>(Kt + l15 * 64 + l4 * 8);
      const bf16x8 kf01 = *reinterpret_cast<const bf16x8*>(Kt + l15 * 64 + 32 + l4 * 8);
      s0 = __builtin_amdgcn_mfma_f32_16x16x32_bf16(qf0, kf00, s0, 0, 0, 0);
      s0 = __builtin_amdgcn_mfma_f32_16x16x32_bf16(qf1, kf01, s0, 0, 0, 0);
      const bf16x8 kf10 = *reinterpret_cast<const bf16x8*>(Kt + (16 + l15) * 64 + l4 * 8);
      const bf16x8 kf11 = *reinterpret_cast<const bf16x8*>(Kt + (16 + l15) * 64 + 32 + l4 * 8);
      s1 = __builtin_amdgcn_mfma_f32_16x16x32_bf16(qf0, kf10, s1, 0, 0, 0);
      s1 = __builtin_amdgcn_mfma_f32_16x16x32_bf16(qf1, kf11, s1, 0, 0, 0);
    }

    // online softmax over this 32-key tile (rows spread over 16-lane groups)
    float fac[4];
#pragma unroll
    for (int r = 0; r < 4; r++) {
      float a0 = s0[r] * 0.125f, a1 = s1[r] * 0.125f;
      float mx = fmaxf(a0, a1);
#pragma unroll
      for (int msk = 1; msk < 16; msk <<= 1) mx = fmaxf(mx, __shfl_xor(mx, msk));
      const float mn = fmaxf(mrow[r], mx);
      const float f = __expf(mrow[r] - mn);
      const float p0 = __expf(a0 - mn), p1 = __expf(a1 - mn);
      float ps = p0 + p1;
#pragma unroll
      for (int msk = 1; msk < 16; msk <<= 1) ps += __shfl_xor(ps, msk);
      lrow[r] = lrow[r] * f + ps;
      mrow[r] = mn;
      fac[r] = f;
      s0[r] = p0;
      s1[r] = p1;
    }
#pragma unroll
    for (int dc = 0; dc < 4; dc++) {
      accO[dc][0] *= fac[0]; accO[dc][1] *= fac[1];
      accO[dc][2] *= fac[2]; accO[dc][3] *= fac[3];
    }

    // P (C-layout) -> LDS -> A-layout fragment (wave-private, no barrier)
    bf16* pw = Pb[w];
#pragma unroll
    for (int r = 0; r < 4; r++) {
      pw[(l4 * 4 + r) * 32 + l15]      = (bf16)s0[r];
      pw[(l4 * 4 + r) * 32 + 16 + l15] = (bf16)s1[r];
    }
    const bf16x8 pf = *reinterpret_cast<const bf16x8*>(pw + l15 * 32 + l4 * 8);

    // O += P @ V   (4 d-chunks of 16)
#pragma unroll
    for (int dc = 0; dc < 4; dc++) {
      const int d = dc * 16 + l15;
      const bf16x8 vf = *reinterpret_cast<const bf16x8*>(
          Vt + d * 32 + ((l4 ^ ((d >> 3) & 3)) * 8));
      accO[dc] = __builtin_amdgcn_mfma_f32_16x16x32_bf16(pf, vf, accO[dc], 0, 0, 0);
    }
  }

#pragma unroll
  for (int dc = 0; dc < 4; dc++) {
#pragma unroll
    for (int r = 0; r < 4; r++) {
      const int t = qb * 64 + w * 16 + l4 * 4 + r;
      out[(size_t)t * C_EMB + h * 64 + dc * 16 + l15] = (bf16)(accO[dc][r] / lrow[r]);
    }
  }
}

// ------------------------------------------------------------------ launch
extern "C" void kernel_launch(void* const* d_in, const int* in_sizes, int n_in,
                              void* d_out, int out_size, void* d_ws, size_t ws_size,
                              hipStream_t stream) {
  const float* x       = (const float*)d_in[0];
  const float* W_kqv   = (const float*)d_in[1];
  const float* W_proj  = (const float*)d_in[2];
  const float* W_fc    = (const float*)d_in[3];
  const float* b_fc    = (const float*)d_in[4];
  const float* W_cproj = (const float*)d_in[5];
  float* outp = (float*)d_out;

  char* p = (char*)d_ws;
  bf16* Wkqv_t  = (bf16*)p; p += (size_t)2304 * 768 * 2;
  bf16* Wproj_t = (bf16*)p; p += (size_t)768 * 768 * 2;
  bf16* Wfc_t   = (bf16*)p; p += (size_t)1536 * 768 * 2;
  bf16* Wcp_t   = (bf16*)p; p += (size_t)768 * 1536 * 2;
  bf16* A1      = (bf16*)p; p += (size_t)4096 * 768 * 2;   // aliased: attn_out
  bf16* KQV     = (bf16*)p; p += (size_t)4096 * 2304 * 2;  // aliased: A2 | Hg
  float* x1     = (float*)p; p += (size_t)4096 * 768 * 4;
  bf16* attn_o = A1;
  bf16* A2     = KQV;
  bf16* Hg     = KQV + (size_t)4096 * 768;

  // weights: f32 [K][N] -> bf16 [N][K]
  wt_transpose<<<dim3(2304 / 32, 768 / 32), 256, 0, stream>>>(W_kqv, Wkqv_t, 768, 2304);
  wt_transpose<<<dim3(768 / 32, 768 / 32), 256, 0, stream>>>(W_proj, Wproj_t, 768, 768);
  wt_transpose<<<dim3(1536 / 32, 768 / 32), 256, 0, stream>>>(W_fc, Wfc_t, 768, 1536);
  wt_transpose<<<dim3(768 / 32, 1536 / 32), 256, 0, stream>>>(W_cproj, Wcp_t, 1536, 768);

  ln_rows<<<4096, 256, 0, stream>>>(x, A1);
  gemm_bt<0><<<dim3(32, 18), 256, 0, stream>>>(A1, Wkqv_t, KQV, nullptr, nullptr,
                                               4096, 2304, 768);
  attn_fused<<<dim3(64, 12), 256, 0, stream>>>(KQV, attn_o);
  gemm_bt<1><<<dim3(32, 6), 256, 0, stream>>>(attn_o, Wproj_t, x1, x, nullptr,
                                              4096, 768, 768);
  ln_rows<<<4096, 256, 0, stream>>>(x1, A2);
  gemm_bt<2><<<dim3(32, 12), 256, 0, stream>>>(A2, Wfc_t, Hg, nullptr, b_fc,
                                               4096, 1536, 768);
  gemm_bt<3><<<dim3(32, 6), 256, 0, stream>>>(Hg, Wcp_t, outp, x1, nullptr,
                                              4096, 768, 1536);
}

// Round 2
// 257.440 us; speedup vs baseline: 1.6185x; 1.6185x over previous
//
#include <hip/hip_runtime.h>
#include <hip/hip_bf16.h>
#include <math.h>

#define T_SEQ 4096
#define C_EMB 768
#define NHEAD 12
#define HDIM  64

typedef __bf16 bf16;
typedef __bf16 bf16x8 __attribute__((ext_vector_type(8)));
typedef __bf16 bf16x4 __attribute__((ext_vector_type(4)));
typedef float  f32x4  __attribute__((ext_vector_type(4)));

// ---------------------------------------------------------------- utilities

__device__ __forceinline__ void stage16(const void* g, void* ldsbase) {
  // global -> LDS direct, 16B per lane; LDS dest = wave-uniform base + lane*16
  __builtin_amdgcn_global_load_lds(
      (__attribute__((address_space(1))) const unsigned int*)g,
      (__attribute__((address_space(3))) unsigned int*)ldsbase, 16, 0, 0);
}

// -------------------------------------------------- weight convert+transpose
// W [K][N] f32  ->  Wt [N][K] bf16
__global__ void wt_transpose(const float* __restrict__ W, bf16* __restrict__ Wt,
                             int K, int N) {
  __shared__ float tile[32][33];
  const int n0 = blockIdx.x * 32, k0 = blockIdx.y * 32;
  const int tx = threadIdx.x & 31, ty = threadIdx.x >> 5;  // 256 thr: ty 0..7
#pragma unroll
  for (int i = 0; i < 32; i += 8)
    tile[ty + i][tx] = W[(size_t)(k0 + ty + i) * N + n0 + tx];
  __syncthreads();
#pragma unroll
  for (int i = 0; i < 32; i += 8)
    Wt[(size_t)(n0 + ty + i) * K + k0 + tx] = (bf16)tile[tx][ty + i];
}

// ------------------------------------------------------------------ layernorm
// x [4096][768] f32 -> y bf16
__global__ void ln_rows(const float* __restrict__ x, bf16* __restrict__ y) {
  const int row = blockIdx.x;
  const float* xr = x + (size_t)row * C_EMB;
  const int t = threadIdx.x;  // 256
  float v0 = xr[t], v1 = xr[t + 256], v2 = xr[t + 512];
  float s  = v0 + v1 + v2;
  float ss = v0 * v0 + v1 * v1 + v2 * v2;
#pragma unroll
  for (int m = 1; m < 64; m <<= 1) {
    s += __shfl_xor(s, m);
    ss += __shfl_xor(ss, m);
  }
  __shared__ float bs[4], bq[4];
  const int w = t >> 6;
  if ((t & 63) == 0) { bs[w] = s; bq[w] = ss; }
  __syncthreads();
  s  = bs[0] + bs[1] + bs[2] + bs[3];
  ss = bq[0] + bq[1] + bq[2] + bq[3];
  const float mu  = s * (1.0f / C_EMB);
  const float var = ss * (1.0f / C_EMB) - mu * mu;
  const float rs  = rsqrtf(var + 1e-5f);
  bf16* yr = y + (size_t)row * C_EMB;
  yr[t]       = (bf16)((v0 - mu) * rs);
  yr[t + 256] = (bf16)((v1 - mu) * rs);
  yr[t + 512] = (bf16)((v2 - mu) * rs);
}

// ------------------------------------------------------------------ GEMM
// C[M][N] = A[M][K](bf16 rowmajor) x BT[N][K](bf16)   (i.e. A @ B)
// EPI 0: store bf16        EPI 1: f32 = res + acc
// EPI 2: bf16 = gelu(acc + bias[c])   EPI 3: f32 = res + acc
template <int EPI>
__global__ void gemm_bt(const bf16* __restrict__ A, const bf16* __restrict__ BT,
                        void* __restrict__ Cout, const float* __restrict__ res,
                        const float* __restrict__ bias, int M, int N, int K) {
  __shared__ __align__(16) bf16 As[128 * 32];
  __shared__ __align__(16) bf16 Bs[128 * 32];
  const int row0 = blockIdx.x * 128, col0 = blockIdx.y * 128;
  const int tid = threadIdx.x;
  const int w = tid >> 6, lane = tid & 63;
  const int wr = w >> 1, wc = w & 1;
  const int l15 = lane & 15, l4 = lane >> 4;

  f32x4 acc[4][4];
#pragma unroll
  for (int m = 0; m < 4; m++)
#pragma unroll
    for (int n = 0; n < 4; n++) acc[m][n] = (f32x4){0.f, 0.f, 0.f, 0.f};

  const int rr = lane >> 2;        // 16 rows per 1KB wave-instr
  const int c8 = (lane & 3) * 8;   // 4 chunks of 8 bf16 per 64B row

  for (int k0 = 0; k0 < K; k0 += 32) {
    const bf16* gA = A + (size_t)(row0 + w * 32 + rr) * K + k0 + c8;
    const bf16* gB = BT + (size_t)(col0 + w * 32 + rr) * K + k0 + c8;
    stage16(gA, As + (w * 32) * 32);
    stage16(gA + (size_t)16 * K, As + (w * 32 + 16) * 32);
    stage16(gB, Bs + (w * 32) * 32);
    stage16(gB + (size_t)16 * K, Bs + (w * 32 + 16) * 32);
    __syncthreads();

    bf16x8 af[4], bfv[4];
#pragma unroll
    for (int m = 0; m < 4; m++)
      af[m] = *reinterpret_cast<const bf16x8*>(As + (wr * 64 + m * 16 + l15) * 32 + l4 * 8);
#pragma unroll
    for (int n = 0; n < 4; n++)
      bfv[n] = *reinterpret_cast<const bf16x8*>(Bs + (wc * 64 + n * 16 + l15) * 32 + l4 * 8);
#pragma unroll
    for (int m = 0; m < 4; m++)
#pragma unroll
      for (int n = 0; n < 4; n++)
        acc[m][n] = __builtin_amdgcn_mfma_f32_16x16x32_bf16(af[m], bfv[n], acc[m][n], 0, 0, 0);
    __syncthreads();
  }

  const int orow = row0 + wr * 64;
  const int ocol = col0 + wc * 64;
#pragma unroll
  for (int m = 0; m < 4; m++) {
#pragma unroll
    for (int n = 0; n < 4; n++) {
      const int c = ocol + n * 16 + l15;
#pragma unroll
      for (int j = 0; j < 4; j++) {
        const int r = orow + m * 16 + l4 * 4 + j;  // C/D: col=lane&15, row=(lane>>4)*4+reg
        const size_t idx = (size_t)r * N + c;
        const float v = acc[m][n][j];
        if (EPI == 0) {
          ((bf16*)Cout)[idx] = (bf16)v;
        } else if (EPI == 1) {
          ((float*)Cout)[idx] = res[idx] + v;
        } else if (EPI == 2) {
          const float h = v + bias[c];
          ((bf16*)Cout)[idx] = (bf16)(0.5f * h * (1.0f + erff(h * 0.70710678118f)));
        } else {
          ((float*)Cout)[idx] = res[idx] + v;
        }
      }
    }
  }
}

// ------------------------------------------------------------------ attention
// kqv [T][2304] bf16 : k at +0, q at +768, v at +1536, head offset h*64
// out [T][768] bf16
//
// Block = 4 waves x 16 q-rows (QB=64); KV tile = 128 keys, 32 iterations.
// Swapped QK^T: S^T = mfma(A=K, B=Q) -> lane owns one q (col=l15); softmax is
// per-lane + 2 shfl_xor. K staged via global_load_lds with PRE-SWIZZLED global
// source (LDS dest linear); all LDS reads use the (row&7)<<4 XOR swizzle.
__global__ void attn_fused(const bf16* __restrict__ kqv, bf16* __restrict__ out) {
  const int qb = blockIdx.x, h = blockIdx.y;
  const int tid = threadIdx.x, w = tid >> 6, lane = tid & 63;
  const int l15 = lane & 15, l4 = lane >> 4;

  __shared__ __align__(16) bf16 Ks[128 * 64];      // [key][d], chunk-swizzled
  __shared__ __align__(16) bf16 Vt[64 * 128];      // [d][key], chunk-swizzled
  __shared__ __align__(16) bf16 Pb[4][16 * 128];   // per-wave P [q][key]

  char* const KsB = (char*)Ks;
  char* const VtB = (char*)Vt;
  char* const PbB = (char*)(Pb[w]);

  // Q fragments (B operand): lane l15 = q row, l4*8 = d chunk
  const int qrow = qb * 64 + w * 16 + l15;
  const bf16* qp = kqv + (size_t)qrow * 2304 + 768 + h * 64 + l4 * 8;
  const bf16x8 qf0 = *reinterpret_cast<const bf16x8*>(qp);
  const bf16x8 qf1 = *reinterpret_cast<const bf16x8*>(qp + 32);

  float mrun = -1e30f, lrun = 0.f;
  f32x4 accO[4];
#pragma unroll
  for (int dt = 0; dt < 4; dt++) accO[dt] = (f32x4){0.f, 0.f, 0.f, 0.f};

  // K staging: lane covers (key = base + lane/8, chunk = (lane&7) ^ (key&7))
  const int srow = lane >> 3;
  const int schunk = (lane & 7) ^ srow;
  // V staging: thread owns keys 4*kb..+3, d 8*db..+7
  const int kb = tid & 31, db = tid >> 5;
  const float cscale = 0.125f * 1.4426950408889634f;  // scale * log2(e)
  const int sw = (l15 & 7) << 4;

  for (int kt = 0; kt < 32; kt++) {
    __syncthreads();
    // ---- stage K tile (16KB) via global_load_lds, source pre-swizzled
#pragma unroll
    for (int c = 0; c < 4; c++) {
      const int keyb = w * 32 + c * 8;
      const bf16* src =
          kqv + (size_t)(kt * 128 + keyb + srow) * 2304 + h * 64 + schunk * 8;
      stage16(src, KsB + (size_t)keyb * 128);
    }
    // ---- stage V tile transposed (reg 4x8 gather -> ds_write_b64)
    {
      const bf16* vb =
          kqv + (size_t)(kt * 128 + kb * 4) * 2304 + 1536 + h * 64 + db * 8;
      const bf16x8 v0 = *reinterpret_cast<const bf16x8*>(vb);
      const bf16x8 v1 = *reinterpret_cast<const bf16x8*>(vb + 2304);
      const bf16x8 v2 = *reinterpret_cast<const bf16x8*>(vb + 4608);
      const bf16x8 v3 = *reinterpret_cast<const bf16x8*>(vb + 6912);
#pragma unroll
      for (int e = 0; e < 8; e++) {
        const bf16x4 pk4 = (bf16x4){v0[e], v1[e], v2[e], v3[e]};
        *reinterpret_cast<bf16x4*>(VtB + (db * 8 + e) * 256 + ((kb * 8) ^ (e << 4))) = pk4;
      }
    }
    __syncthreads();

    // ---- S^T = K @ Q^T : 8 key-tiles of 16, K-reduce over d=64 (2 MFMA each)
    f32x4 st[8];
#pragma unroll
    for (int t = 0; t < 8; t++) {
      const char* kr = KsB + (16 * t + l15) * 128;
      const bf16x8 kf0 = *reinterpret_cast<const bf16x8*>(kr + ((l4 * 16) ^ sw));
      const bf16x8 kf1 = *reinterpret_cast<const bf16x8*>(kr + ((64 + l4 * 16) ^ sw));
      f32x4 a = (f32x4){0.f, 0.f, 0.f, 0.f};
      a = __builtin_amdgcn_mfma_f32_16x16x32_bf16(kf0, qf0, a, 0, 0, 0);
      a = __builtin_amdgcn_mfma_f32_16x16x32_bf16(kf1, qf1, a, 0, 0, 0);
      st[t] = a;
    }

    // ---- online softmax (per-lane q; keys spread over 4 l4-groups)
    float amax = -1e30f;
#pragma unroll
    for (int t = 0; t < 8; t++)
#pragma unroll
      for (int r = 0; r < 4; r++) {
        st[t][r] *= cscale;
        amax = fmaxf(amax, st[t][r]);
      }
    amax = fmaxf(amax, __shfl_xor(amax, 16));
    amax = fmaxf(amax, __shfl_xor(amax, 32));
    const float mn = fmaxf(mrun, amax);
    const float fac = exp2f(mrun - mn);
    mrun = mn;
    float ps = 0.f;
#pragma unroll
    for (int t = 0; t < 8; t++)
#pragma unroll
      for (int r = 0; r < 4; r++) {
        st[t][r] = exp2f(st[t][r] - mn);
        ps += st[t][r];
      }
    ps += __shfl_xor(ps, 16);
    ps += __shfl_xor(ps, 32);
    lrun = lrun * fac + ps;
#pragma unroll
    for (int dt = 0; dt < 4; dt++) accO[dt] *= fac;

    // ---- P -> LDS (bf16, swizzled b64 writes; wave-private, no barrier)
#pragma unroll
    for (int t = 0; t < 8; t++) {
      const bf16x4 pk4 = (bf16x4){(bf16)st[t][0], (bf16)st[t][1],
                                  (bf16)st[t][2], (bf16)st[t][3]};
      *reinterpret_cast<bf16x4*>(PbB + l15 * 256 + ((t * 32 + l4 * 8) ^ sw)) = pk4;
    }

    // ---- O^T += V^T @ P^T : 4 key-chunks of 32 x 4 d-tiles of 16
#pragma unroll
    for (int kc = 0; kc < 4; kc++) {
      const bf16x8 pf = *reinterpret_cast<const bf16x8*>(
          PbB + l15 * 256 + ((kc * 64 + l4 * 16) ^ sw));
#pragma unroll
      for (int dt = 0; dt < 4; dt++) {
        const bf16x8 vf = *reinterpret_cast<const bf16x8*>(
            VtB + (dt * 16 + l15) * 256 + ((kc * 64 + l4 * 16) ^ sw));
        accO[dt] = __builtin_amdgcn_mfma_f32_16x16x32_bf16(vf, pf, accO[dt], 0, 0, 0);
      }
    }
  }

  // ---- epilogue: O^T layout col=l15=q, row=l4*4+r = d-within-tile
  const float inv = 1.0f / lrun;
#pragma unroll
  for (int dt = 0; dt < 4; dt++) {
    const bf16x4 o4 = (bf16x4){(bf16)(accO[dt][0] * inv), (bf16)(accO[dt][1] * inv),
                               (bf16)(accO[dt][2] * inv), (bf16)(accO[dt][3] * inv)};
    *reinterpret_cast<bf16x4*>(out + (size_t)qrow * C_EMB + h * 64 + dt * 16 + l4 * 4) = o4;
  }
}

// ------------------------------------------------------------------ launch
extern "C" void kernel_launch(void* const* d_in, const int* in_sizes, int n_in,
                              void* d_out, int out_size, void* d_ws, size_t ws_size,
                              hipStream_t stream) {
  const float* x       = (const float*)d_in[0];
  const float* W_kqv   = (const float*)d_in[1];
  const float* W_proj  = (const float*)d_in[2];
  const float* W_fc    = (const float*)d_in[3];
  const float* b_fc    = (const float*)d_in[4];
  const float* W_cproj = (const float*)d_in[5];
  float* outp = (float*)d_out;

  char* p = (char*)d_ws;
  bf16* Wkqv_t  = (bf16*)p; p += (size_t)2304 * 768 * 2;
  bf16* Wproj_t = (bf16*)p; p += (size_t)768 * 768 * 2;
  bf16* Wfc_t   = (bf16*)p; p += (size_t)1536 * 768 * 2;
  bf16* Wcp_t   = (bf16*)p; p += (size_t)768 * 1536 * 2;
  bf16* A1      = (bf16*)p; p += (size_t)4096 * 768 * 2;   // aliased: attn_out
  bf16* KQV     = (bf16*)p; p += (size_t)4096 * 2304 * 2;  // aliased: A2 | Hg
  float* x1     = (float*)p; p += (size_t)4096 * 768 * 4;
  bf16* attn_o = A1;
  bf16* A2     = KQV;
  bf16* Hg     = KQV + (size_t)4096 * 768;

  // weights: f32 [K][N] -> bf16 [N][K]
  wt_transpose<<<dim3(2304 / 32, 768 / 32), 256, 0, stream>>>(W_kqv, Wkqv_t, 768, 2304);
  wt_transpose<<<dim3(768 / 32, 768 / 32), 256, 0, stream>>>(W_proj, Wproj_t, 768, 768);
  wt_transpose<<<dim3(1536 / 32, 768 / 32), 256, 0, stream>>>(W_fc, Wfc_t, 768, 1536);
  wt_transpose<<<dim3(768 / 32, 1536 / 32), 256, 0, stream>>>(W_cproj, Wcp_t, 1536, 768);

  ln_rows<<<4096, 256, 0, stream>>>(x, A1);
  gemm_bt<0><<<dim3(32, 18), 256, 0, stream>>>(A1, Wkqv_t, KQV, nullptr, nullptr,
                                               4096, 2304, 768);
  attn_fused<<<dim3(64, 12), 256, 0, stream>>>(KQV, attn_o);
  gemm_bt<1><<<dim3(32, 6), 256, 0, stream>>>(attn_o, Wproj_t, x1, x, nullptr,
                                              4096, 768, 768);
  ln_rows<<<4096, 256, 0, stream>>>(x1, A2);
  gemm_bt<2><<<dim3(32, 12), 256, 0, stream>>>(A2, Wfc_t, Hg, nullptr, b_fc,
                                               4096, 1536, 768);
  gemm_bt<3><<<dim3(32, 6), 256, 0, stream>>>(Hg, Wcp_t, outp, x1, nullptr,
                                              4096, 768, 1536);
}

// Round 3
// 237.131 us; speedup vs baseline: 1.7571x; 1.0856x over previous
//
#include <hip/hip_runtime.h>
#include <hip/hip_bf16.h>
#include <math.h>

#define T_SEQ 4096
#define C_EMB 768
#define NHEAD 12
#define HDIM  64

typedef __bf16 bf16;
typedef __bf16 bf16x8 __attribute__((ext_vector_type(8)));
typedef __bf16 bf16x4 __attribute__((ext_vector_type(4)));
typedef float  f32x4  __attribute__((ext_vector_type(4)));

// ---------------------------------------------------------------- utilities

__device__ __forceinline__ void stage16(const void* g, void* ldsbase) {
  // global -> LDS direct, 16B per lane; LDS dest = wave-uniform base + lane*16
  __builtin_amdgcn_global_load_lds(
      (__attribute__((address_space(1))) const unsigned int*)g,
      (__attribute__((address_space(3))) unsigned int*)ldsbase, 16, 0, 0);
}

// -------------------------------------------------- weight convert+transpose
// W [K][N] f32  ->  Wt [N][K] bf16
__global__ void wt_transpose(const float* __restrict__ W, bf16* __restrict__ Wt,
                             int K, int N) {
  __shared__ float tile[32][33];
  const int n0 = blockIdx.x * 32, k0 = blockIdx.y * 32;
  const int tx = threadIdx.x & 31, ty = threadIdx.x >> 5;  // 256 thr: ty 0..7
#pragma unroll
  for (int i = 0; i < 32; i += 8)
    tile[ty + i][tx] = W[(size_t)(k0 + ty + i) * N + n0 + tx];
  __syncthreads();
#pragma unroll
  for (int i = 0; i < 32; i += 8)
    Wt[(size_t)(n0 + ty + i) * K + k0 + tx] = (bf16)tile[tx][ty + i];
}

// ------------------------------------------------------------------ layernorm
// x [4096][768] f32 -> y bf16
__global__ void ln_rows(const float* __restrict__ x, bf16* __restrict__ y) {
  const int row = blockIdx.x;
  const float* xr = x + (size_t)row * C_EMB;
  const int t = threadIdx.x;  // 256
  float v0 = xr[t], v1 = xr[t + 256], v2 = xr[t + 512];
  float s  = v0 + v1 + v2;
  float ss = v0 * v0 + v1 * v1 + v2 * v2;
#pragma unroll
  for (int m = 1; m < 64; m <<= 1) {
    s += __shfl_xor(s, m);
    ss += __shfl_xor(ss, m);
  }
  __shared__ float bs[4], bq[4];
  const int w = t >> 6;
  if ((t & 63) == 0) { bs[w] = s; bq[w] = ss; }
  __syncthreads();
  s  = bs[0] + bs[1] + bs[2] + bs[3];
  ss = bq[0] + bq[1] + bq[2] + bq[3];
  const float mu  = s * (1.0f / C_EMB);
  const float var = ss * (1.0f / C_EMB) - mu * mu;
  const float rs  = rsqrtf(var + 1e-5f);
  bf16* yr = y + (size_t)row * C_EMB;
  yr[t]       = (bf16)((v0 - mu) * rs);
  yr[t + 256] = (bf16)((v1 - mu) * rs);
  yr[t + 512] = (bf16)((v2 - mu) * rs);
}

// ------------------------------------------------------------------ GEMM
// C[M][N] = A[M][K](bf16 rowmajor) x BT[N][K](bf16)   (i.e. A @ B)
// EPI 0: store bf16        EPI 1: f32 = res + acc
// EPI 2: bf16 = gelu(acc + bias[c])   EPI 3: f32 = res + acc
template <int EPI>
__global__ void gemm_bt(const bf16* __restrict__ A, const bf16* __restrict__ BT,
                        void* __restrict__ Cout, const float* __restrict__ res,
                        const float* __restrict__ bias, int M, int N, int K) {
  __shared__ __align__(16) bf16 As[128 * 32];
  __shared__ __align__(16) bf16 Bs[128 * 32];
  const int row0 = blockIdx.x * 128, col0 = blockIdx.y * 128;
  const int tid = threadIdx.x;
  const int w = tid >> 6, lane = tid & 63;
  const int wr = w >> 1, wc = w & 1;
  const int l15 = lane & 15, l4 = lane >> 4;

  f32x4 acc[4][4];
#pragma unroll
  for (int m = 0; m < 4; m++)
#pragma unroll
    for (int n = 0; n < 4; n++) acc[m][n] = (f32x4){0.f, 0.f, 0.f, 0.f};

  const int rr = lane >> 2;        // 16 rows per 1KB wave-instr
  const int c8 = (lane & 3) * 8;   // 4 chunks of 8 bf16 per 64B row

  for (int k0 = 0; k0 < K; k0 += 32) {
    const bf16* gA = A + (size_t)(row0 + w * 32 + rr) * K + k0 + c8;
    const bf16* gB = BT + (size_t)(col0 + w * 32 + rr) * K + k0 + c8;
    stage16(gA, As + (w * 32) * 32);
    stage16(gA + (size_t)16 * K, As + (w * 32 + 16) * 32);
    stage16(gB, Bs + (w * 32) * 32);
    stage16(gB + (size_t)16 * K, Bs + (w * 32 + 16) * 32);
    __syncthreads();

    bf16x8 af[4], bfv[4];
#pragma unroll
    for (int m = 0; m < 4; m++)
      af[m] = *reinterpret_cast<const bf16x8*>(As + (wr * 64 + m * 16 + l15) * 32 + l4 * 8);
#pragma unroll
    for (int n = 0; n < 4; n++)
      bfv[n] = *reinterpret_cast<const bf16x8*>(Bs + (wc * 64 + n * 16 + l15) * 32 + l4 * 8);
#pragma unroll
    for (int m = 0; m < 4; m++)
#pragma unroll
      for (int n = 0; n < 4; n++)
        acc[m][n] = __builtin_amdgcn_mfma_f32_16x16x32_bf16(af[m], bfv[n], acc[m][n], 0, 0, 0);
    __syncthreads();
  }

  const int orow = row0 + wr * 64;
  const int ocol = col0 + wc * 64;
#pragma unroll
  for (int m = 0; m < 4; m++) {
#pragma unroll
    for (int n = 0; n < 4; n++) {
      const int c = ocol + n * 16 + l15;
#pragma unroll
      for (int j = 0; j < 4; j++) {
        const int r = orow + m * 16 + l4 * 4 + j;  // C/D: col=lane&15, row=(lane>>4)*4+reg
        const size_t idx = (size_t)r * N + c;
        const float v = acc[m][n][j];
        if (EPI == 0) {
          ((bf16*)Cout)[idx] = (bf16)v;
        } else if (EPI == 1) {
          ((float*)Cout)[idx] = res[idx] + v;
        } else if (EPI == 2) {
          const float h = v + bias[c];
          ((bf16*)Cout)[idx] = (bf16)(0.5f * h * (1.0f + erff(h * 0.70710678118f)));
        } else {
          ((float*)Cout)[idx] = res[idx] + v;
        }
      }
    }
  }
}

// ------------------------------------------------------------------ attention
// kqv [T][2304] bf16 : k at +0, q at +768, v at +1536, head offset h*64
// out [T][768] bf16
//
// Block = 4 waves x 16 q-rows (QB=64); KV tile = 128 keys, 32 iterations.
// Swapped QK^T (S^T = mfma(K,Q)); softmax per-lane in log2 domain (Q is
// pre-scaled by 0.125*log2e); defer-max rescale (THR=11.5).
//
// Key-relabel trick: position p (QK^T row) holds key label
// l(p) = bit-perm [b5 b4 b3 b2 | b6 | b1 b0] of p. V is stored at Vt[d][l(p)]
// during staging, so the PV B-fragment is exactly the lane-local registers
// pb[j] = st[kc + 4*(j>>2)][j&3] -- no P LDS round-trip, no shuffles.
//
// K and V are reg-staged with cross-iteration prefetch: next tile's global
// loads issue right after the compute barrier and fly during compute.
__global__ void attn_fused(const bf16* __restrict__ kqv, bf16* __restrict__ out) {
  const int qb = blockIdx.x, h = blockIdx.y;
  const int tid = threadIdx.x, w = tid >> 6, lane = tid & 63;
  const int l15 = lane & 15, l4 = lane >> 4;

  __shared__ __align__(16) bf16 Ks[128 * 64];   // [pos][d], chunk ^ (pos&7)
  __shared__ __align__(16) bf16 Vt[64 * 128];   // [d][label], chunk ^ (d&7)
  char* const KsB = (char*)Ks;
  char* const VtB = (char*)Vt;

  // Q fragments (B operand), pre-scaled by scale*log2(e)
  const int qrow = qb * 64 + w * 16 + l15;
  const bf16* qp = kqv + (size_t)qrow * 2304 + 768 + h * 64 + l4 * 8;
  bf16x8 qf0 = *reinterpret_cast<const bf16x8*>(qp);
  bf16x8 qf1 = *reinterpret_cast<const bf16x8*>(qp + 32);
  const float cscale = 0.125f * 1.4426950408889634f;
#pragma unroll
  for (int e = 0; e < 8; e++) {
    qf0[e] = (bf16)((float)qf0[e] * cscale);
    qf1[e] = (bf16)((float)qf1[e] * cscale);
  }

  float mrun = -1e30f, lrun = 0.f;
  f32x4 accO[4];
#pragma unroll
  for (int dt = 0; dt < 4; dt++) accO[dt] = (f32x4){0.f, 0.f, 0.f, 0.f};

  // K staging ownership: row = tid>>1 (0..127), 64B half = tid&1
  const int krow = tid >> 1;
  const int kc0 = (tid & 1) * 4;
  const int swK = krow & 7;
  // V staging ownership: keys kb*4..+3, d = db*8..+7; label base of kb*4
  const int kb = tid & 31, db = tid >> 5;
  const int lb = ((kb >> 2) & 3) * 32 + (kb & 3) * 8 + (kb >> 4) * 4;
  const int lchunk = lb >> 3, lbyte = (lb & 7) * 2;

  bf16x8 kreg0, kreg1, kreg2, kreg3, vreg0, vreg1, vreg2, vreg3;
#define LOADKV(kt)                                                              \
  {                                                                             \
    const bf16* kp = kqv + (size_t)((kt)*128 + krow) * 2304 + h * 64 + kc0 * 8; \
    kreg0 = *reinterpret_cast<const bf16x8*>(kp);                               \
    kreg1 = *reinterpret_cast<const bf16x8*>(kp + 8);                           \
    kreg2 = *reinterpret_cast<const bf16x8*>(kp + 16);                          \
    kreg3 = *reinterpret_cast<const bf16x8*>(kp + 24);                          \
    const bf16* vp =                                                            \
        kqv + (size_t)((kt)*128 + kb * 4) * 2304 + 1536 + h * 64 + db * 8;      \
    vreg0 = *reinterpret_cast<const bf16x8*>(vp);                               \
    vreg1 = *reinterpret_cast<const bf16x8*>(vp + 2304);                        \
    vreg2 = *reinterpret_cast<const bf16x8*>(vp + 4608);                        \
    vreg3 = *reinterpret_cast<const bf16x8*>(vp + 6912);                        \
  }

  LOADKV(0);
  const int sw = (l15 & 7) << 4;

  for (int kt = 0; kt < 32; kt++) {
    __syncthreads();
    // ---- LDS writes from registers (no global latency inside barriers)
    {
      char* kdst = KsB + krow * 128;
      *reinterpret_cast<bf16x8*>(kdst + (((kc0 + 0) ^ swK) << 4)) = kreg0;
      *reinterpret_cast<bf16x8*>(kdst + (((kc0 + 1) ^ swK) << 4)) = kreg1;
      *reinterpret_cast<bf16x8*>(kdst + (((kc0 + 2) ^ swK) << 4)) = kreg2;
      *reinterpret_cast<bf16x8*>(kdst + (((kc0 + 3) ^ swK) << 4)) = kreg3;
#pragma unroll
      for (int e = 0; e < 8; e++) {
        const int d = db * 8 + e;
        const bf16x4 pk4 = (bf16x4){vreg0[e], vreg1[e], vreg2[e], vreg3[e]};
        *reinterpret_cast<bf16x4*>(VtB + d * 256 + ((lchunk ^ (d & 7)) << 4) + lbyte) = pk4;
      }
    }
    __syncthreads();
    if (kt + 1 < 32) LOADKV(kt + 1);  // prefetch flies during compute

    // ---- S^T = K @ Q^T : 8 pos-tiles of 16, reduce over d=64 (2 MFMA each)
    f32x4 st[8];
#pragma unroll
    for (int t = 0; t < 8; t++) {
      const char* kr = KsB + (16 * t + l15) * 128;
      const bf16x8 kf0 = *reinterpret_cast<const bf16x8*>(kr + ((l4 * 16) ^ sw));
      const bf16x8 kf1 = *reinterpret_cast<const bf16x8*>(kr + ((64 + l4 * 16) ^ sw));
      f32x4 a = (f32x4){0.f, 0.f, 0.f, 0.f};
      a = __builtin_amdgcn_mfma_f32_16x16x32_bf16(kf0, qf0, a, 0, 0, 0);
      a = __builtin_amdgcn_mfma_f32_16x16x32_bf16(kf1, qf1, a, 0, 0, 0);
      st[t] = a;
    }

    // ---- online softmax, log2 domain, defer-max
    float amax = -1e30f;
#pragma unroll
    for (int t = 0; t < 8; t++)
#pragma unroll
      for (int r = 0; r < 4; r++) amax = fmaxf(amax, st[t][r]);
    amax = fmaxf(amax, __shfl_xor(amax, 16));
    amax = fmaxf(amax, __shfl_xor(amax, 32));
    if (!__all(amax <= mrun + 11.5f)) {
      const float mn = fmaxf(mrun, amax);
      const float fac = exp2f(mrun - mn);
      mrun = mn;
      lrun *= fac;
#pragma unroll
      for (int dt = 0; dt < 4; dt++) accO[dt] *= fac;
    }
    float ps = 0.f;
#pragma unroll
    for (int t = 0; t < 8; t++)
#pragma unroll
      for (int r = 0; r < 4; r++) {
        st[t][r] = exp2f(st[t][r] - mrun);
        ps += st[t][r];
      }
    ps += __shfl_xor(ps, 16);
    ps += __shfl_xor(ps, 32);
    lrun += ps;

    // ---- O^T += V^T @ P^T : B-frag is lane-local via key relabeling
#pragma unroll
    for (int kc = 0; kc < 4; kc++) {
      bf16x8 pb;
      pb[0] = (bf16)st[kc][0];
      pb[1] = (bf16)st[kc][1];
      pb[2] = (bf16)st[kc][2];
      pb[3] = (bf16)st[kc][3];
      pb[4] = (bf16)st[kc + 4][0];
      pb[5] = (bf16)st[kc + 4][1];
      pb[6] = (bf16)st[kc + 4][2];
      pb[7] = (bf16)st[kc + 4][3];
#pragma unroll
      for (int dt = 0; dt < 4; dt++) {
        const bf16x8 vf = *reinterpret_cast<const bf16x8*>(
            VtB + (dt * 16 + l15) * 256 + (((kc * 4 + l4) ^ (l15 & 7)) << 4));
        accO[dt] = __builtin_amdgcn_mfma_f32_16x16x32_bf16(vf, pb, accO[dt], 0, 0, 0);
      }
    }
  }
#undef LOADKV

  // ---- epilogue: O^T layout col=l15=q, row=l4*4+r = d-within-tile
  const float inv = 1.0f / lrun;
#pragma unroll
  for (int dt = 0; dt < 4; dt++) {
    const bf16x4 o4 = (bf16x4){(bf16)(accO[dt][0] * inv), (bf16)(accO[dt][1] * inv),
                               (bf16)(accO[dt][2] * inv), (bf16)(accO[dt][3] * inv)};
    *reinterpret_cast<bf16x4*>(out + (size_t)qrow * C_EMB + h * 64 + dt * 16 + l4 * 4) = o4;
  }
}

// ------------------------------------------------------------------ launch
extern "C" void kernel_launch(void* const* d_in, const int* in_sizes, int n_in,
                              void* d_out, int out_size, void* d_ws, size_t ws_size,
                              hipStream_t stream) {
  const float* x       = (const float*)d_in[0];
  const float* W_kqv   = (const float*)d_in[1];
  const float* W_proj  = (const float*)d_in[2];
  const float* W_fc    = (const float*)d_in[3];
  const float* b_fc    = (const float*)d_in[4];
  const float* W_cproj = (const float*)d_in[5];
  float* outp = (float*)d_out;

  char* p = (char*)d_ws;
  bf16* Wkqv_t  = (bf16*)p; p += (size_t)2304 * 768 * 2;
  bf16* Wproj_t = (bf16*)p; p += (size_t)768 * 768 * 2;
  bf16* Wfc_t   = (bf16*)p; p += (size_t)1536 * 768 * 2;
  bf16* Wcp_t   = (bf16*)p; p += (size_t)768 * 1536 * 2;
  bf16* A1      = (bf16*)p; p += (size_t)4096 * 768 * 2;   // aliased: attn_out
  bf16* KQV     = (bf16*)p; p += (size_t)4096 * 2304 * 2;  // aliased: A2 | Hg
  float* x1     = (float*)p; p += (size_t)4096 * 768 * 4;
  bf16* attn_o = A1;
  bf16* A2     = KQV;
  bf16* Hg     = KQV + (size_t)4096 * 768;

  // weights: f32 [K][N] -> bf16 [N][K]
  wt_transpose<<<dim3(2304 / 32, 768 / 32), 256, 0, stream>>>(W_kqv, Wkqv_t, 768, 2304);
  wt_transpose<<<dim3(768 / 32, 768 / 32), 256, 0, stream>>>(W_proj, Wproj_t, 768, 768);
  wt_transpose<<<dim3(1536 / 32, 768 / 32), 256, 0, stream>>>(W_fc, Wfc_t, 768, 1536);
  wt_transpose<<<dim3(768 / 32, 1536 / 32), 256, 0, stream>>>(W_cproj, Wcp_t, 1536, 768);

  ln_rows<<<4096, 256, 0, stream>>>(x, A1);
  gemm_bt<0><<<dim3(32, 18), 256, 0, stream>>>(A1, Wkqv_t, KQV, nullptr, nullptr,
                                               4096, 2304, 768);
  attn_fused<<<dim3(64, 12), 256, 0, stream>>>(KQV, attn_o);
  gemm_bt<1><<<dim3(32, 6), 256, 0, stream>>>(attn_o, Wproj_t, x1, x, nullptr,
                                              4096, 768, 768);
  ln_rows<<<4096, 256, 0, stream>>>(x1, A2);
  gemm_bt<2><<<dim3(32, 12), 256, 0, stream>>>(A2, Wfc_t, Hg, nullptr, b_fc,
                                               4096, 1536, 768);
  gemm_bt<3><<<dim3(32, 6), 256, 0, stream>>>(Hg, Wcp_t, outp, x1, nullptr,
                                              4096, 768, 1536);
}

// Round 4
// 228.937 us; speedup vs baseline: 1.8200x; 1.0358x over previous
//
#include <hip/hip_runtime.h>
#include <hip/hip_bf16.h>
#include <math.h>

#define T_SEQ 4096
#define C_EMB 768
#define NHEAD 12
#define HDIM  64

typedef __bf16 bf16;
typedef __bf16 bf16x8 __attribute__((ext_vector_type(8)));
typedef __bf16 bf16x4 __attribute__((ext_vector_type(4)));
typedef float  f32x4  __attribute__((ext_vector_type(4)));

// ---------------------------------------------------------------- utilities

__device__ __forceinline__ void stage16(const void* g, void* ldsbase) {
  // global -> LDS direct, 16B per lane; LDS dest = wave-uniform base + lane*16
  __builtin_amdgcn_global_load_lds(
      (__attribute__((address_space(1))) const unsigned int*)g,
      (__attribute__((address_space(3))) unsigned int*)ldsbase, 16, 0, 0);
}

// -------------------------------------------------- weight convert+transpose
// W [K][N] f32  ->  Wt [N][K] bf16
__global__ void wt_transpose(const float* __restrict__ W, bf16* __restrict__ Wt,
                             int K, int N) {
  __shared__ float tile[32][33];
  const int n0 = blockIdx.x * 32, k0 = blockIdx.y * 32;
  const int tx = threadIdx.x & 31, ty = threadIdx.x >> 5;  // 256 thr: ty 0..7
#pragma unroll
  for (int i = 0; i < 32; i += 8)
    tile[ty + i][tx] = W[(size_t)(k0 + ty + i) * N + n0 + tx];
  __syncthreads();
#pragma unroll
  for (int i = 0; i < 32; i += 8)
    Wt[(size_t)(n0 + ty + i) * K + k0 + tx] = (bf16)tile[tx][ty + i];
}

// ------------------------------------------------------------------ layernorm
// x [4096][768] f32 -> y bf16
__global__ void ln_rows(const float* __restrict__ x, bf16* __restrict__ y) {
  const int row = blockIdx.x;
  const float* xr = x + (size_t)row * C_EMB;
  const int t = threadIdx.x;  // 256
  float v0 = xr[t], v1 = xr[t + 256], v2 = xr[t + 512];
  float s  = v0 + v1 + v2;
  float ss = v0 * v0 + v1 * v1 + v2 * v2;
#pragma unroll
  for (int m = 1; m < 64; m <<= 1) {
    s += __shfl_xor(s, m);
    ss += __shfl_xor(ss, m);
  }
  __shared__ float bs[4], bq[4];
  const int w = t >> 6;
  if ((t & 63) == 0) { bs[w] = s; bq[w] = ss; }
  __syncthreads();
  s  = bs[0] + bs[1] + bs[2] + bs[3];
  ss = bq[0] + bq[1] + bq[2] + bq[3];
  const float mu  = s * (1.0f / C_EMB);
  const float var = ss * (1.0f / C_EMB) - mu * mu;
  const float rs  = rsqrtf(var + 1e-5f);
  bf16* yr = y + (size_t)row * C_EMB;
  yr[t]       = (bf16)((v0 - mu) * rs);
  yr[t + 256] = (bf16)((v1 - mu) * rs);
  yr[t + 512] = (bf16)((v2 - mu) * rs);
}

// ------------------------------------------------------------------ GEMM
// C[M][N] = A[M][K](bf16 rowmajor) x BT[N][K](bf16)   (i.e. A @ B)
// 2-phase double-buffered pipeline: prefetch tile i+1 via global_load_lds
// BEFORE computing tile i; raw s_barrier + manual vmcnt(0) so the prefetch
// flies during the MFMA phase (HIP __syncthreads would drain it).
// EPI 0: store bf16        EPI 1: f32 = res + acc
// EPI 2: bf16 = gelu(acc + bias[c])   EPI 3: f32 = res + acc
template <int EPI>
__global__ void gemm_bt(const bf16* __restrict__ A, const bf16* __restrict__ BT,
                        void* __restrict__ Cout, const float* __restrict__ res,
                        const float* __restrict__ bias, int M, int N, int K) {
  __shared__ __align__(16) bf16 As[2][128 * 32];
  __shared__ __align__(16) bf16 Bs[2][128 * 32];
  const int row0 = blockIdx.x * 128, col0 = blockIdx.y * 128;
  const int tid = threadIdx.x;
  const int w = tid >> 6, lane = tid & 63;
  const int wr = w >> 1, wc = w & 1;
  const int l15 = lane & 15, l4 = lane >> 4;

  f32x4 acc[4][4];
#pragma unroll
  for (int m = 0; m < 4; m++)
#pragma unroll
    for (int n = 0; n < 4; n++) acc[m][n] = (f32x4){0.f, 0.f, 0.f, 0.f};

  const int rr = lane >> 2;        // 16 rows per 1KB wave-instr
  const int c8 = (lane & 3) * 8;   // 4 chunks of 8 bf16 per 64B row

#define STAGE(b, k0)                                                       \
  {                                                                        \
    const bf16* gA = A + (size_t)(row0 + w * 32 + rr) * K + (k0) + c8;     \
    const bf16* gB = BT + (size_t)(col0 + w * 32 + rr) * K + (k0) + c8;    \
    stage16(gA, As[b] + (w * 32) * 32);                                    \
    stage16(gA + (size_t)16 * K, As[b] + (w * 32 + 16) * 32);              \
    stage16(gB, Bs[b] + (w * 32) * 32);                                    \
    stage16(gB + (size_t)16 * K, Bs[b] + (w * 32 + 16) * 32);              \
  }

  const int nk = K >> 5;
  STAGE(0, 0);
  asm volatile("s_waitcnt vmcnt(0)" ::: "memory");
  __builtin_amdgcn_s_barrier();

  for (int i = 0; i < nk; i++) {
    const int cur = i & 1;
    if (i + 1 < nk) STAGE(cur ^ 1, (i + 1) * 32);

    bf16x8 af[4], bfv[4];
#pragma unroll
    for (int m = 0; m < 4; m++)
      af[m] = *reinterpret_cast<const bf16x8*>(As[cur] + (wr * 64 + m * 16 + l15) * 32 + l4 * 8);
#pragma unroll
    for (int n = 0; n < 4; n++)
      bfv[n] = *reinterpret_cast<const bf16x8*>(Bs[cur] + (wc * 64 + n * 16 + l15) * 32 + l4 * 8);
#pragma unroll
    for (int m = 0; m < 4; m++)
#pragma unroll
      for (int n = 0; n < 4; n++)
        acc[m][n] = __builtin_amdgcn_mfma_f32_16x16x32_bf16(af[m], bfv[n], acc[m][n], 0, 0, 0);

    if (i + 1 < nk) {
      asm volatile("s_waitcnt vmcnt(0)" ::: "memory");
      __builtin_amdgcn_s_barrier();
    }
  }
#undef STAGE

  const int orow = row0 + wr * 64;
  const int ocol = col0 + wc * 64;
#pragma unroll
  for (int m = 0; m < 4; m++) {
#pragma unroll
    for (int n = 0; n < 4; n++) {
      const int c = ocol + n * 16 + l15;
#pragma unroll
      for (int j = 0; j < 4; j++) {
        const int r = orow + m * 16 + l4 * 4 + j;  // C/D: col=lane&15, row=(lane>>4)*4+reg
        const size_t idx = (size_t)r * N + c;
        const float v = acc[m][n][j];
        if (EPI == 0) {
          ((bf16*)Cout)[idx] = (bf16)v;
        } else if (EPI == 1) {
          ((float*)Cout)[idx] = res[idx] + v;
        } else if (EPI == 2) {
          const float h = v + bias[c];
          ((bf16*)Cout)[idx] = (bf16)(0.5f * h * (1.0f + erff(h * 0.70710678118f)));
        } else {
          ((float*)Cout)[idx] = res[idx] + v;
        }
      }
    }
  }
}

// ------------------------------------------------------------------ attention
// kqv [T][2304] bf16 : k at +0, q at +768, v at +1536, head offset h*64
// out [T][768] bf16
//
// Block = 4 waves x 16 q-rows (QB=64); KV tile = 128 keys, 32 iterations.
// Swapped QK^T (S^T = mfma(K,Q)); Q pre-scaled by 0.125*log2e (log2 domain).
// mrun folded into QK^T C-operand (acc init = -mrun): the common no-rescale
// path (defer-max, THR=11.5) computes P = exp2(st) with ZERO subtracts.
// lrun via the MFMA ones-trick: accL = mfma(ones, P, accL) makes every output
// row = sum_k P[k][q], so every lane holds the row sum -- no shuffles.
//
// Key-relabel trick: position p holds key label l(p) = bit-perm
// [b5 b4 b3 b2 | b6 | b1 b0] of p; V stored at Vt[d][l(p)] so the PV B-frag
// is lane-local registers. K/V reg-staged with cross-iteration prefetch.
__global__ void attn_fused(const bf16* __restrict__ kqv, bf16* __restrict__ out) {
  const int qb = blockIdx.x, h = blockIdx.y;
  const int tid = threadIdx.x, w = tid >> 6, lane = tid & 63;
  const int l15 = lane & 15, l4 = lane >> 4;

  __shared__ __align__(16) bf16 Ks[128 * 64];   // [pos][d], chunk ^ (pos&7)
  __shared__ __align__(16) bf16 Vt[64 * 128];   // [d][label], chunk ^ (d&7)
  char* const KsB = (char*)Ks;
  char* const VtB = (char*)Vt;

  // Q fragments (B operand), pre-scaled by scale*log2(e)
  const int qrow = qb * 64 + w * 16 + l15;
  const bf16* qp = kqv + (size_t)qrow * 2304 + 768 + h * 64 + l4 * 8;
  bf16x8 qf0 = *reinterpret_cast<const bf16x8*>(qp);
  bf16x8 qf1 = *reinterpret_cast<const bf16x8*>(qp + 32);
  const float cscale = 0.125f * 1.4426950408889634f;
#pragma unroll
  for (int e = 0; e < 8; e++) {
    qf0[e] = (bf16)((float)qf0[e] * cscale);
    qf1[e] = (bf16)((float)qf1[e] * cscale);
  }
  bf16x8 ones;
#pragma unroll
  for (int e = 0; e < 8; e++) ones[e] = (bf16)1.0f;

  float mrun = 0.f;
  f32x4 accL = (f32x4){0.f, 0.f, 0.f, 0.f};
  f32x4 accO[4];
#pragma unroll
  for (int dt = 0; dt < 4; dt++) accO[dt] = (f32x4){0.f, 0.f, 0.f, 0.f};

  // K staging ownership: row = tid>>1 (0..127), 64B half = tid&1
  const int krow = tid >> 1;
  const int kc0 = (tid & 1) * 4;
  const int swK = krow & 7;
  // V staging ownership: keys kb*4..+3, d = db*8..+7; label base of kb*4
  const int kb = tid & 31, db = tid >> 5;
  const int lb = ((kb >> 2) & 3) * 32 + (kb & 3) * 8 + (kb >> 4) * 4;
  const int lchunk = lb >> 3, lbyte = (lb & 7) * 2;

  bf16x8 kreg0, kreg1, kreg2, kreg3, vreg0, vreg1, vreg2, vreg3;
#define LOADKV(kt)                                                              \
  {                                                                             \
    const bf16* kp = kqv + (size_t)((kt)*128 + krow) * 2304 + h * 64 + kc0 * 8; \
    kreg0 = *reinterpret_cast<const bf16x8*>(kp);                               \
    kreg1 = *reinterpret_cast<const bf16x8*>(kp + 8);                           \
    kreg2 = *reinterpret_cast<const bf16x8*>(kp + 16);                          \
    kreg3 = *reinterpret_cast<const bf16x8*>(kp + 24);                          \
    const bf16* vp =                                                            \
        kqv + (size_t)((kt)*128 + kb * 4) * 2304 + 1536 + h * 64 + db * 8;      \
    vreg0 = *reinterpret_cast<const bf16x8*>(vp);                               \
    vreg1 = *reinterpret_cast<const bf16x8*>(vp + 2304);                        \
    vreg2 = *reinterpret_cast<const bf16x8*>(vp + 4608);                        \
    vreg3 = *reinterpret_cast<const bf16x8*>(vp + 6912);                        \
  }

  LOADKV(0);
  const int sw = (l15 & 7) << 4;

  for (int kt = 0; kt < 32; kt++) {
    __syncthreads();
    // ---- LDS writes from registers (no global latency inside barriers)
    {
      char* kdst = KsB + krow * 128;
      *reinterpret_cast<bf16x8*>(kdst + (((kc0 + 0) ^ swK) << 4)) = kreg0;
      *reinterpret_cast<bf16x8*>(kdst + (((kc0 + 1) ^ swK) << 4)) = kreg1;
      *reinterpret_cast<bf16x8*>(kdst + (((kc0 + 2) ^ swK) << 4)) = kreg2;
      *reinterpret_cast<bf16x8*>(kdst + (((kc0 + 3) ^ swK) << 4)) = kreg3;
#pragma unroll
      for (int e = 0; e < 8; e++) {
        const int d = db * 8 + e;
        const bf16x4 pk4 = (bf16x4){vreg0[e], vreg1[e], vreg2[e], vreg3[e]};
        *reinterpret_cast<bf16x4*>(VtB + d * 256 + ((lchunk ^ (d & 7)) << 4) + lbyte) = pk4;
      }
    }
    __syncthreads();
    if (kt + 1 < 32) LOADKV(kt + 1);  // prefetch flies during compute

    // ---- S^T = K @ Q^T, C-init = -mrun : st = s*scale*log2e - mrun
    f32x4 st[8];
#pragma unroll
    for (int t = 0; t < 8; t++) {
      const char* kr = KsB + (16 * t + l15) * 128;
      const bf16x8 kf0 = *reinterpret_cast<const bf16x8*>(kr + ((l4 * 16) ^ sw));
      const bf16x8 kf1 = *reinterpret_cast<const bf16x8*>(kr + ((64 + l4 * 16) ^ sw));
      f32x4 a = (f32x4){-mrun, -mrun, -mrun, -mrun};
      a = __builtin_amdgcn_mfma_f32_16x16x32_bf16(kf0, qf0, a, 0, 0, 0);
      a = __builtin_amdgcn_mfma_f32_16x16x32_bf16(kf1, qf1, a, 0, 0, 0);
      st[t] = a;
    }

    // ---- defer-max online softmax (log2 domain)
    float amax = st[0][0];
#pragma unroll
    for (int t = 0; t < 8; t++)
#pragma unroll
      for (int r = 0; r < 4; r++) amax = fmaxf(amax, st[t][r]);
    amax = fmaxf(amax, __shfl_xor(amax, 16));
    amax = fmaxf(amax, __shfl_xor(amax, 32));
    if (!__all(amax <= 11.5f)) {   // rare rescale path
      const float dsh = fmaxf(amax, 0.f);
      const float fac = exp2f(-dsh);
      mrun += dsh;
#pragma unroll
      for (int t = 0; t < 8; t++)
#pragma unroll
        for (int r = 0; r < 4; r++) st[t][r] -= dsh;
#pragma unroll
      for (int dt = 0; dt < 4; dt++) accO[dt] *= fac;
      accL *= fac;
    }
#pragma unroll
    for (int t = 0; t < 8; t++)
#pragma unroll
      for (int r = 0; r < 4; r++) st[t][r] = exp2f(st[t][r]);

    // ---- O^T += V^T @ P^T ; accL += ones @ P^T (row-sum in every lane)
#pragma unroll
    for (int kc = 0; kc < 4; kc++) {
      bf16x8 pb;
      pb[0] = (bf16)st[kc][0];
      pb[1] = (bf16)st[kc][1];
      pb[2] = (bf16)st[kc][2];
      pb[3] = (bf16)st[kc][3];
      pb[4] = (bf16)st[kc + 4][0];
      pb[5] = (bf16)st[kc + 4][1];
      pb[6] = (bf16)st[kc + 4][2];
      pb[7] = (bf16)st[kc + 4][3];
#pragma unroll
      for (int dt = 0; dt < 4; dt++) {
        const bf16x8 vf = *reinterpret_cast<const bf16x8*>(
            VtB + (dt * 16 + l15) * 256 + (((kc * 4 + l4) ^ (l15 & 7)) << 4));
        accO[dt] = __builtin_amdgcn_mfma_f32_16x16x32_bf16(vf, pb, accO[dt], 0, 0, 0);
      }
      accL = __builtin_amdgcn_mfma_f32_16x16x32_bf16(ones, pb, accL, 0, 0, 0);
    }
  }
#undef LOADKV

  // ---- epilogue: O^T layout col=l15=q, row=l4*4+r = d-within-tile
  const float inv = 1.0f / accL[0];
#pragma unroll
  for (int dt = 0; dt < 4; dt++) {
    const bf16x4 o4 = (bf16x4){(bf16)(accO[dt][0] * inv), (bf16)(accO[dt][1] * inv),
                               (bf16)(accO[dt][2] * inv), (bf16)(accO[dt][3] * inv)};
    *reinterpret_cast<bf16x4*>(out + (size_t)qrow * C_EMB + h * 64 + dt * 16 + l4 * 4) = o4;
  }
}

// ------------------------------------------------------------------ launch
extern "C" void kernel_launch(void* const* d_in, const int* in_sizes, int n_in,
                              void* d_out, int out_size, void* d_ws, size_t ws_size,
                              hipStream_t stream) {
  const float* x       = (const float*)d_in[0];
  const float* W_kqv   = (const float*)d_in[1];
  const float* W_proj  = (const float*)d_in[2];
  const float* W_fc    = (const float*)d_in[3];
  const float* b_fc    = (const float*)d_in[4];
  const float* W_cproj = (const float*)d_in[5];
  float* outp = (float*)d_out;

  char* p = (char*)d_ws;
  bf16* Wkqv_t  = (bf16*)p; p += (size_t)2304 * 768 * 2;
  bf16* Wproj_t = (bf16*)p; p += (size_t)768 * 768 * 2;
  bf16* Wfc_t   = (bf16*)p; p += (size_t)1536 * 768 * 2;
  bf16* Wcp_t   = (bf16*)p; p += (size_t)768 * 1536 * 2;
  bf16* A1      = (bf16*)p; p += (size_t)4096 * 768 * 2;   // aliased: attn_out
  bf16* KQV     = (bf16*)p; p += (size_t)4096 * 2304 * 2;  // aliased: A2 | Hg
  float* x1     = (float*)p; p += (size_t)4096 * 768 * 4;
  bf16* attn_o = A1;
  bf16* A2     = KQV;
  bf16* Hg     = KQV + (size_t)4096 * 768;

  // weights: f32 [K][N] -> bf16 [N][K]
  wt_transpose<<<dim3(2304 / 32, 768 / 32), 256, 0, stream>>>(W_kqv, Wkqv_t, 768, 2304);
  wt_transpose<<<dim3(768 / 32, 768 / 32), 256, 0, stream>>>(W_proj, Wproj_t, 768, 768);
  wt_transpose<<<dim3(1536 / 32, 768 / 32), 256, 0, stream>>>(W_fc, Wfc_t, 768, 1536);
  wt_transpose<<<dim3(768 / 32, 1536 / 32), 256, 0, stream>>>(W_cproj, Wcp_t, 1536, 768);

  ln_rows<<<4096, 256, 0, stream>>>(x, A1);
  gemm_bt<0><<<dim3(32, 18), 256, 0, stream>>>(A1, Wkqv_t, KQV, nullptr, nullptr,
                                               4096, 2304, 768);
  attn_fused<<<dim3(64, 12), 256, 0, stream>>>(KQV, attn_o);
  gemm_bt<1><<<dim3(32, 6), 256, 0, stream>>>(attn_o, Wproj_t, x1, x, nullptr,
                                              4096, 768, 768);
  ln_rows<<<4096, 256, 0, stream>>>(x1, A2);
  gemm_bt<2><<<dim3(32, 12), 256, 0, stream>>>(A2, Wfc_t, Hg, nullptr, b_fc,
                                               4096, 1536, 768);
  gemm_bt<3><<<dim3(32, 6), 256, 0, stream>>>(Hg, Wcp_t, outp, x1, nullptr,
                                              4096, 768, 1536);
}